// Round 1
// baseline (227.952 us; speedup 1.0000x reference)
//
#include <hip/hip_runtime.h>

// GNN_Critic: 2-layer SAGEConv (F: 1 -> 16 -> 1) + global_add_pool.
// p[n] = h[n,:].W2l (edge-aggregated -> s2), q[n] = h[n,:].W2r; the 16-dim
// hidden vector is never materialized.
//
// Round-5: bin passes were gather-latency-bound at 1 block/CU (grid was
// PP*CBIN = 256 = exactly one 16-wave block per CU). CBIN 16 -> 32 doubles
// the bin grid to 512 blocks -> 2 blocks/CU -> 32 waves/CU (the hardware
// wave ceiling), doubling the TLP available to hide the 6.4M random x[src]/
// pv[src] L2 gathers. __launch_bounds__(BLK, 8) caps VGPRs at 64 so the
// second block is actually resident (2 x 50KB LDS = 100KB <= 160KB ok).
// Slab traffic grows 12.8 -> 25.6 MB (+~4us); everything else unchanged.

#define PP        16            // node parts / buckets
#define BLK       1024
#define SCAP      1024u         // per-part LDS staging ring capacity (u32)
#define SMASK     1023u
#define TILE      (BLK * 4)     // 4096 edges per partition block
#define CBIN      32            // slab chunks per part (was 16)
#define CNT_ONE   (1u << 25)    // pass-1 count field bits [31:25]
#define FX_BIAS   131072        // 2^17 per-add bias keeps sum field positive
#define SCALE     4096.0f       // 2^12 fixed-point scale
#define INV_SCALE (1.0f / 4096.0f)

// ---------------------------------------------------------------------------
// Counting partition: one tile of 4096 edges per block. Stage packed words in
// per-part LDS rings, drain coalesced with one tail-atomic per part.
__global__ __launch_bounds__(BLK) void partition_kernel(
    const int* __restrict__ ei, unsigned* __restrict__ pairs,
    unsigned* __restrict__ tails, int E, int bins, unsigned Mdiv, int cap) {
    extern __shared__ unsigned buf[];                 // [PP][SCAP] = 64 KB
    __shared__ unsigned cnt[PP], base[PP], fq[PP], gb[PP];
    const int tid = threadIdx.x;
    if (tid < PP) { cnt[tid] = 0; base[tid] = 0; }
    __syncthreads();

    int b0 = blockIdx.x * TILE;
    int e0 = b0 + tid * 4;
    int nv = E - e0; nv = nv < 0 ? 0 : (nv > 4 ? 4 : nv);
    int srcv[4], dstv[4];
    if (nv == 4 && ((E & 3) == 0)) {
        int4 s = *(const int4*)(ei + e0);
        int4 d = *(const int4*)(ei + E + e0);
        srcv[0] = s.x; srcv[1] = s.y; srcv[2] = s.z; srcv[3] = s.w;
        dstv[0] = d.x; dstv[1] = d.y; dstv[2] = d.z; dstv[3] = d.w;
    } else {
        for (int j = 0; j < nv; ++j) { srcv[j] = ei[e0 + j]; dstv[j] = ei[E + e0 + j]; }
    }
    unsigned w[4]; int part[4]; bool pend[4];
    for (int j = 0; j < 4; ++j) {
        pend[j] = (j < nv);
        if (pend[j]) {
            unsigned dst = (unsigned)dstv[j];
            unsigned pt = (unsigned)(((unsigned long long)dst * Mdiv) >> 32);
            int ld = (int)dst - (int)pt * bins;
            while (ld >= bins) { ld -= bins; ++pt; }
            while (ld < 0)     { ld += bins; --pt; }
            part[j] = (int)pt;
            w[j] = ((unsigned)srcv[j] << 14) | (unsigned)ld;
        }
    }
    // insertion (overflow cannot occur for random input; retry loop is the
    // correctness guarantee for pathological part skew)
    for (int j = 0; j < 4; ++j) {
        if (pend[j]) {
            unsigned slot = atomicAdd(&cnt[part[j]], 1u);
            if (slot - base[part[j]] < SCAP) {
                buf[part[j] * SCAP + (slot & SMASK)] = w[j]; pend[j] = false;
            } else atomicSub(&cnt[part[j]], 1u);
        }
    }
    int npend = __syncthreads_count((int)(pend[0] | pend[1] | pend[2] | pend[3]));
    while (npend > 0) {
        if (tid < PP) {
            unsigned avail = cnt[tid] - base[tid];
            unsigned f = avail & ~511u;
            fq[tid] = f;
            if (f) gb[tid] = atomicAdd(&tails[tid], f);
        }
        __syncthreads();
        {
            int wv = tid >> 6, lane = tid & 63;
            unsigned f = fq[wv];
            if (f) {
                unsigned g0 = gb[wv], bs = base[wv];
                unsigned mx = (g0 + f <= (unsigned)cap) ? f : ((unsigned)cap > g0 ? (unsigned)cap - g0 : 0u);
                unsigned* dp = pairs + (size_t)wv * cap + g0;
                for (unsigned jj = lane; jj < mx; jj += 64)
                    dp[jj] = buf[wv * SCAP + ((bs + jj) & SMASK)];
            }
        }
        __syncthreads();
        if (tid < PP) base[tid] += fq[tid];
        __syncthreads();
        for (int j = 0; j < 4; ++j) {
            if (pend[j]) {
                unsigned slot = atomicAdd(&cnt[part[j]], 1u);
                if (slot - base[part[j]] < SCAP) {
                    buf[part[j] * SCAP + (slot & SMASK)] = w[j]; pend[j] = false;
                } else atomicSub(&cnt[part[j]], 1u);
            }
        }
        npend = __syncthreads_count((int)(pend[0] | pend[1] | pend[2] | pend[3]));
    }
    // final drain
    if (tid < PP) {
        unsigned avail = cnt[tid] - base[tid];
        fq[tid] = avail;
        if (avail) gb[tid] = atomicAdd(&tails[tid], avail);
    }
    __syncthreads();
    {
        int wv = tid >> 6, lane = tid & 63;
        unsigned f = fq[wv];
        if (f) {
            unsigned g0 = gb[wv], bs = base[wv];
            unsigned mx = (g0 + f <= (unsigned)cap) ? f : ((unsigned)cap > g0 ? (unsigned)cap - g0 : 0u);
            unsigned* dp = pairs + (size_t)wv * cap + g0;
            for (unsigned jj = lane; jj < mx; jj += 64)
                dp[jj] = buf[wv * SCAP + ((bs + jj) & SMASK)];
        }
    }
}

// ---------------------------------------------------------------------------
// Bin pass 1: bins[ld] += pack(count=1, x[src]) over this (part, chunk).
// __launch_bounds__(BLK, 8): 8 waves/EU -> 2 blocks/CU resident (VGPR <= 64).
__global__ __launch_bounds__(BLK, 8) void bin1_kernel(
    const unsigned* __restrict__ pairs, const unsigned* __restrict__ tails,
    const float* __restrict__ x, unsigned* __restrict__ slab,
    int N, int bins, int cap) {
    extern __shared__ unsigned sb[];
    int p = blockIdx.x & (PP - 1);
    int c = blockIdx.x / PP;
    int len = (int)tails[p]; if (len > cap) len = cap;
    int st = (int)((long long)len * c / CBIN);
    int en = (int)((long long)len * (c + 1) / CBIN);
    for (int j = threadIdx.x; j < bins; j += BLK) sb[j] = 0;
    __syncthreads();
    const unsigned* bp = pairs + (size_t)p * cap;
    int st4 = (st + 3) & ~3;
    int en4 = en & ~3;
    int preEnd = st4 < en ? st4 : en;
    for (int e = st + (int)threadIdx.x; e < preEnd; e += BLK) {
        unsigned wv = bp[e];
        atomicAdd(&sb[wv & 16383u],
                  CNT_ONE + (unsigned)((int)rintf(x[wv >> 14] * SCALE) + FX_BIAS));
    }
    if (st4 < en4) {
        const uint4* bp4 = (const uint4*)(bp + st4);
        int n4 = (en4 - st4) >> 2;
        for (int e = threadIdx.x; e < n4; e += BLK) {
            uint4 wq = bp4[e];
            atomicAdd(&sb[wq.x & 16383u],
                      CNT_ONE + (unsigned)((int)rintf(x[wq.x >> 14] * SCALE) + FX_BIAS));
            atomicAdd(&sb[wq.y & 16383u],
                      CNT_ONE + (unsigned)((int)rintf(x[wq.y >> 14] * SCALE) + FX_BIAS));
            atomicAdd(&sb[wq.z & 16383u],
                      CNT_ONE + (unsigned)((int)rintf(x[wq.z >> 14] * SCALE) + FX_BIAS));
            atomicAdd(&sb[wq.w & 16383u],
                      CNT_ONE + (unsigned)((int)rintf(x[wq.w >> 14] * SCALE) + FX_BIAS));
        }
    }
    int tailSt = st4 > en4 ? st4 : en4;
    for (int e = tailSt + (int)threadIdx.x; e < en; e += BLK) {
        unsigned wv = bp[e];
        atomicAdd(&sb[wv & 16383u],
                  CNT_ONE + (unsigned)((int)rintf(x[wv >> 14] * SCALE) + FX_BIAS));
    }
    __syncthreads();
    unsigned* dst = slab + (size_t)c * N + (size_t)p * bins;
    int nb = N - p * bins; if (nb > bins) nb = bins;
    for (int j = threadIdx.x; j < nb; j += BLK) dst[j] = sb[j];
}

// ---------------------------------------------------------------------------
// Bin pass 2: bins[ld] += fix(p[src])  (signed i32)
__global__ __launch_bounds__(BLK, 8) void bin2_kernel(
    const unsigned* __restrict__ pairs, const unsigned* __restrict__ tails,
    const float* __restrict__ pv, int* __restrict__ slab,
    int N, int bins, int cap) {
    extern __shared__ int sbi[];
    int p = blockIdx.x & (PP - 1);
    int c = blockIdx.x / PP;
    int len = (int)tails[p]; if (len > cap) len = cap;
    int st = (int)((long long)len * c / CBIN);
    int en = (int)((long long)len * (c + 1) / CBIN);
    for (int j = threadIdx.x; j < bins; j += BLK) sbi[j] = 0;
    __syncthreads();
    const unsigned* bp = pairs + (size_t)p * cap;
    int st4 = (st + 3) & ~3;
    int en4 = en & ~3;
    int preEnd = st4 < en ? st4 : en;
    for (int e = st + (int)threadIdx.x; e < preEnd; e += BLK) {
        unsigned wv = bp[e];
        atomicAdd(&sbi[wv & 16383u], (int)rintf(pv[wv >> 14] * SCALE));
    }
    if (st4 < en4) {
        const uint4* bp4 = (const uint4*)(bp + st4);
        int n4 = (en4 - st4) >> 2;
        for (int e = threadIdx.x; e < n4; e += BLK) {
            uint4 wq = bp4[e];
            atomicAdd(&sbi[wq.x & 16383u], (int)rintf(pv[wq.x >> 14] * SCALE));
            atomicAdd(&sbi[wq.y & 16383u], (int)rintf(pv[wq.y >> 14] * SCALE));
            atomicAdd(&sbi[wq.z & 16383u], (int)rintf(pv[wq.z >> 14] * SCALE));
            atomicAdd(&sbi[wq.w & 16383u], (int)rintf(pv[wq.w >> 14] * SCALE));
        }
    }
    int tailSt = st4 > en4 ? st4 : en4;
    for (int e = tailSt + (int)threadIdx.x; e < en; e += BLK) {
        unsigned wv = bp[e];
        atomicAdd(&sbi[wv & 16383u], (int)rintf(pv[wv >> 14] * SCALE));
    }
    __syncthreads();
    int* dst = slab + (size_t)c * N + (size_t)p * bins;
    int nb = N - p * bins; if (nb > bins) nb = bins;
    for (int j = threadIdx.x; j < nb; j += BLK) dst[j] = sbi[j];
}

// ---------------------------------------------------------------------------
// Node pass 1: reduce CBIN slab entries -> (sum1, deg); compute
// h[f] = relu(mean1*W1l[f] + b1[f] + x*W1r[f]); p = h.W2l, q = h.W2r.
__global__ void node_pass1_kernel(const float* __restrict__ x,
                                  const unsigned* __restrict__ slab,
                                  const float* __restrict__ W1l,
                                  const float* __restrict__ b1,
                                  const float* __restrict__ W1r,
                                  const float* __restrict__ W2l,
                                  const float* __restrict__ W2r,
                                  float* __restrict__ deg_out,
                                  float* __restrict__ pv,
                                  float* __restrict__ qv,
                                  int N) {
    __shared__ float s_w1l[16], s_b1[16], s_w1r[16], s_w2l[16], s_w2r[16];
    if (threadIdx.x < 16) {
        s_w1l[threadIdx.x] = W1l[threadIdx.x];
        s_b1[threadIdx.x]  = b1[threadIdx.x];
        s_w1r[threadIdx.x] = W1r[threadIdx.x];
        s_w2l[threadIdx.x] = W2l[threadIdx.x];
        s_w2r[threadIdx.x] = W2r[threadIdx.x];
    }
    __syncthreads();
    int n = blockIdx.x * blockDim.x + threadIdx.x;
    if (n >= N) return;

    unsigned cnt = 0, fx = 0;
#pragma unroll
    for (int c = 0; c < CBIN; ++c) {
        unsigned w = slab[(size_t)c * N + n];
        cnt += w >> 25;
        fx  += w & (CNT_ONE - 1);
    }
    float dg  = (float)cnt;
    float sum = (float)(int)(fx - cnt * (unsigned)FX_BIAS) * INV_SCALE;
    float m   = sum / fmaxf(dg, 1.0f);

    float xv = x[n];
    float pa = 0.0f, qa = 0.0f;
#pragma unroll
    for (int f = 0; f < 16; ++f) {
        float h = fmaf(m, s_w1l[f], fmaf(xv, s_w1r[f], s_b1[f]));
        h = fmaxf(h, 0.0f);
        pa = fmaf(h, s_w2l[f], pa);
        qa = fmaf(h, s_w2r[f], qa);
    }
    deg_out[n] = dg;
    pv[n] = pa;
    qv[n] = qa;
}

// ---------------------------------------------------------------------------
// Node pass 2 + pool: s2 = sum_c slab2[c][n]; h2 = s2/max(deg,1) + b2 + q;
// out[batch[n]] += h2 (batch sorted -> wave-segmented reduction).
__global__ void node_pass2_kernel(const int* __restrict__ slab2,
                                  const float* __restrict__ deg,
                                  const float* __restrict__ qv,
                                  const float* __restrict__ b2,
                                  const int* __restrict__ batch,
                                  float* __restrict__ out,
                                  int N) {
    int i = blockIdx.x * blockDim.x + threadIdx.x;
    float b2v = b2[0];
    float val = 0.0f;
    int g;
    if (i < N) {
        int sacc = 0;
#pragma unroll
        for (int c = 0; c < CBIN; ++c) sacc += slab2[(size_t)c * N + i];
        float s2 = (float)sacc * INV_SCALE;
        val = s2 / fmaxf(deg[i], 1.0f) + b2v + qv[i];
        g = batch[i];
    } else {
        g = batch[N - 1];  // pad lanes contribute 0 to a valid graph id
    }
    int g0 = __shfl(g, 0);
    unsigned long long same = __ballot(g == g0);
    if (same == ~0ULL) {
        for (int off = 32; off > 0; off >>= 1) val += __shfl_down(val, off);
        if ((threadIdx.x & 63) == 0) atomicAdd(&out[g0], val);
    } else {
        atomicAdd(&out[g], val);
    }
}

// ---------------------------------------------------------------------------
extern "C" void kernel_launch(void* const* d_in, const int* in_sizes, int n_in,
                              void* d_out, int out_size, void* d_ws, size_t ws_size,
                              hipStream_t stream) {
    const float* x     = (const float*)d_in[0];
    const int*   ei    = (const int*)d_in[1];   // [2, E] flat: src then dst
    const int*   batch = (const int*)d_in[2];
    const float* W1l = (const float*)d_in[4];
    const float* b1  = (const float*)d_in[5];
    const float* W1r = (const float*)d_in[6];
    const float* W2l = (const float*)d_in[7];
    const float* b2  = (const float*)d_in[8];
    const float* W2r = (const float*)d_in[9];

    const int N = in_sizes[0];        // 200000
    const int E = in_sizes[1] / 2;    // 6400000
    float* out = (float*)d_out;       // [512]

    const int bins = (N + PP - 1) / PP;                       // 12500
    const unsigned Mdiv =
        (unsigned)(((1ULL << 32) + (unsigned)bins - 1) / (unsigned)bins);
    const int EperP = E / PP;
    int cap = ((EperP + EperP / 32 + 4096) + 1023) & ~1023;   // ~20-sigma margin

    // workspace (u32 words): pairs[PP][cap] | slab[CBIN][N] | deg|p|q (f32) | tails[PP]
    unsigned* pairs = (unsigned*)d_ws;
    unsigned* slab1 = pairs + (size_t)PP * cap;
    int*      slab2 = (int*)slab1;
    float* deg = (float*)(slab1 + (size_t)CBIN * N);
    float* pv  = deg + N;
    float* qv  = pv + N;
    unsigned* tails = (unsigned*)(qv + N);

    hipMemsetAsync(d_out, 0, (size_t)out_size * sizeof(float), stream);
    hipMemsetAsync(tails, 0, PP * sizeof(unsigned), stream);

    const int partShmem = PP * (int)SCAP * 4;   // 65536 B
    const int binShmem  = bins * 4;             // 50000 B
    hipFuncSetAttribute((const void*)partition_kernel,
                        hipFuncAttributeMaxDynamicSharedMemorySize, partShmem);
    hipFuncSetAttribute((const void*)bin1_kernel,
                        hipFuncAttributeMaxDynamicSharedMemorySize, binShmem);
    hipFuncSetAttribute((const void*)bin2_kernel,
                        hipFuncAttributeMaxDynamicSharedMemorySize, binShmem);

    int partBlocks = (E + TILE - 1) / TILE;     // 1563
    const int NB = 256;
    int node_blocks = (N + NB - 1) / NB;

    partition_kernel<<<partBlocks, BLK, partShmem, stream>>>(ei, pairs, tails,
                                                             E, bins, Mdiv, cap);
    bin1_kernel<<<PP * CBIN, BLK, binShmem, stream>>>(pairs, tails, x, slab1,
                                                      N, bins, cap);
    node_pass1_kernel<<<node_blocks, NB, 0, stream>>>(x, slab1, W1l, b1, W1r,
                                                      W2l, W2r, deg, pv, qv, N);
    bin2_kernel<<<PP * CBIN, BLK, binShmem, stream>>>(pairs, tails, pv, slab2,
                                                      N, bins, cap);
    node_pass2_kernel<<<node_blocks, NB, 0, stream>>>(slab2, deg, qv, b2, batch,
                                                      out, N);
}